// Round 6
// baseline (654.243 us; speedup 1.0000x reference)
//
#include <hip/hip_runtime.h>

constexpr int BSZ = 8, SEQ = 4096, HID = 1024, NE = 8, CAP = 512;
constexpr int ROWS = BSZ * NE;                          // 64
constexpr size_t IDX_ELEMS = (size_t)ROWS * CAP;        // 32768
constexpr size_t SCR_OFF = IDX_ELEMS;                   // 32768
constexpr size_t MASK_OFF = IDX_ELEMS * 2;              // 65536
constexpr size_t MASK_ELEMS = (size_t)ROWS * CAP * SEQ; // 134217728
constexpr size_t AFF_ELEMS = (size_t)ROWS * SEQ;        // 262144 floats (1 MB)

// ---------------------------------------------------------------------------
// Gating, replicating np.einsum (optimize=False) fp32 SOP semantics:
// contig_contig_outstride0_two @ SSE-baseline (manylinux: SSE2+SSE3, NO FMA):
//   - 4-lane vector accumulator v[j], lane j handles d === j (mod 4),
//     persistent across the whole d=0..1023 loop
//   - blocks of 16, x4-unrolled REVERSED chained mul+add (separate roundings):
//       v = a0*b0 + (a1*b1 + (a2*b2 + (a3*b3 + v)))
//   - horizontal sum npyv_sum_f32 = SSE3 double-hadd: (v0+v1)+(v2+v3)
//     [THE R4->R6 FIX: R4 wrongly used the SSE2 movehl tree (v0+v2)+(v1+v3)]
// Softmax: max (exact), fsub, correctly-rounded fp32 exp (fp64 exp, one
// rounding), numpy pairwise n==8 tree ((p0+p1)+(p2+p3))+((p4+p5)+(p6+p7)),
// fp32 divide.
// Block = 128 threads = 16 tokens x 8 experts; chunks staged in LDS,
// d-order preserved (chunk c ascending, block k ascending).
// ---------------------------------------------------------------------------
__global__ __launch_bounds__(128) void gating_kernel(const float* __restrict__ hidden,
                                                     const float* __restrict__ weight,
                                                     float* __restrict__ aff)
{
    __shared__ float hls[16][68]; // 16 tokens x 64-d chunk (pad to 68)
    __shared__ float wls[8][68];  // transposed weight chunk: [e][dd]
    __shared__ float lls[16][8];  // logits exchange

    const int tid = threadIdx.x;
    const int T0 = blockIdx.x * 16;
    const int t = tid >> 3;       // token within block
    const int e = tid & 7;        // expert

    float v0 = 0.f, v1 = 0.f, v2 = 0.f, v3 = 0.f; // SSE lanes j=0..3
    for (int c = 0; c < 16; ++c) {
        __syncthreads(); // protect previous chunk's reads
        // stage hidden chunk: 256 float4s, coalesced
#pragma unroll
        for (int k = 0; k < 2; ++k) {
            const int j = tid + k * 128;      // 0..255
            const int tt = j >> 4, q = j & 15;
            const float4 v = *(const float4*)(hidden + (size_t)(T0 + tt) * HID + c * 64 + 4 * q);
            *(float4*)&hls[tt][4 * q] = v;
        }
        // stage weight chunk transposed: 512 scalars, coalesced global reads
#pragma unroll
        for (int k = 0; k < 4; ++k) {
            const int j = tid + k * 128;      // 0..511 == dd*8+ee
            const int dd = j >> 3, ee = j & 7;
            wls[ee][dd] = weight[(size_t)(c * 64 + dd) * NE + ee];
        }
        __syncthreads();
        // four 16-float blocks per chunk, numpy SOP order
#pragma unroll
        for (int k = 0; k < 4; ++k) {
            const int base = 16 * k;
            const float4 hA = *(const float4*)&hls[t][base + 0];
            const float4 hB = *(const float4*)&hls[t][base + 4];
            const float4 hC = *(const float4*)&hls[t][base + 8];
            const float4 hD = *(const float4*)&hls[t][base + 12];
            const float4 wA = *(const float4*)&wls[e][base + 0];
            const float4 wB = *(const float4*)&wls[e][base + 4];
            const float4 wC = *(const float4*)&wls[e][base + 8];
            const float4 wD = *(const float4*)&wls[e][base + 12];
            // v = a0*b0 + (a1*b1 + (a2*b2 + (a3*b3 + v))), per lane, no FMA
            v0 = __fadd_rn(__fmul_rn(hA.x, wA.x),
                 __fadd_rn(__fmul_rn(hB.x, wB.x),
                 __fadd_rn(__fmul_rn(hC.x, wC.x),
                 __fadd_rn(__fmul_rn(hD.x, wD.x), v0))));
            v1 = __fadd_rn(__fmul_rn(hA.y, wA.y),
                 __fadd_rn(__fmul_rn(hB.y, wB.y),
                 __fadd_rn(__fmul_rn(hC.y, wC.y),
                 __fadd_rn(__fmul_rn(hD.y, wD.y), v1))));
            v2 = __fadd_rn(__fmul_rn(hA.z, wA.z),
                 __fadd_rn(__fmul_rn(hB.z, wB.z),
                 __fadd_rn(__fmul_rn(hC.z, wC.z),
                 __fadd_rn(__fmul_rn(hD.z, wD.z), v2))));
            v3 = __fadd_rn(__fmul_rn(hA.w, wA.w),
                 __fadd_rn(__fmul_rn(hB.w, wB.w),
                 __fadd_rn(__fmul_rn(hC.w, wC.w),
                 __fadd_rn(__fmul_rn(hD.w, wD.w), v3))));
        }
    }
    // npyv_sum_f32 with SSE3 (manylinux baseline): double hadd = (v0+v1)+(v2+v3)
    const float logit = __fadd_rn(__fadd_rn(v0, v1), __fadd_rn(v2, v3));

    lls[t][e] = logit;
    __syncthreads();

    float l[8];
#pragma unroll
    for (int k = 0; k < 8; ++k) l[k] = lls[t][k];
    float m = l[0];
#pragma unroll
    for (int k = 1; k < 8; ++k) m = fmaxf(m, l[k]);
    float p[8];
#pragma unroll
    for (int k = 0; k < 8; ++k)
        p[k] = (float)exp((double)__fsub_rn(l[k], m)); // correctly-rounded fp32 exp
    const float s = __fadd_rn(__fadd_rn(__fadd_rn(p[0], p[1]), __fadd_rn(p[2], p[3])),
                              __fadd_rn(__fadd_rn(p[4], p[5]), __fadd_rn(p[6], p[7])));
    const float a = __fdiv_rn(p[e], s);

    const int token = T0 + t;
    const int b = token >> 12;
    const int sidx = token & (SEQ - 1);
    aff[((size_t)b * NE + e) * SEQ + sidx] = a;
}

// ---------------------------------------------------------------------------
// Fused top-k + zero-fill. Blocks 0..63: bitonic sort one (b,e) row of 4096
// packed keys (fp32_bits<<32)|(4095-idx) in LDS -- positive fp32 order-
// preserving as uint; descending sort => value-desc, index-asc tie-break
// (stable top_k). Blocks >= 64: grid-stride zero the mask concurrently.
// ---------------------------------------------------------------------------
__global__ __launch_bounds__(512) void topk_zero_kernel(const float* __restrict__ aff,
                                                        float* __restrict__ out,
                                                        long long zero_elems)
{
    __shared__ unsigned long long keys[SEQ]; // 32 KB
    if (blockIdx.x < (unsigned)ROWS) {
        const int row = blockIdx.x;
        const float* a = aff + (size_t)row * SEQ;
        for (int i = threadIdx.x; i < SEQ; i += 512) {
            const unsigned int fb = __float_as_uint(a[i]);
            keys[i] = ((unsigned long long)fb << 32) | (unsigned int)(SEQ - 1 - i);
        }
        for (int len = 2; len <= SEQ; len <<= 1) {
            for (int stride = len >> 1; stride > 0; stride >>= 1) {
                __syncthreads();
                for (int t = threadIdx.x; t < SEQ / 2; t += 512) {
                    const int i = (t << 1) - (t & (stride - 1));
                    const int j = i + stride;
                    const unsigned long long ki = keys[i], kj = keys[j];
                    const bool desc = ((i & len) == 0);
                    if (desc ? (ki < kj) : (ki > kj)) { keys[i] = kj; keys[j] = ki; }
                }
            }
        }
        __syncthreads();
        {
            const int t = threadIdx.x; // 512 == CAP
            const unsigned long long k = keys[t];
            const int idx = (SEQ - 1) - (int)(unsigned int)(k & 0xffffffffu);
            out[(size_t)row * CAP + t] = (float)idx;                         // indices
            out[SCR_OFF + (size_t)row * CAP + t] =
                __uint_as_float((unsigned int)(k >> 32));                    // scores
        }
    } else {
        const long long nz4 = zero_elems >> 2;
        float4* mz = (float4*)(out + MASK_OFF);
        const float4 z4 = make_float4(0.f, 0.f, 0.f, 0.f);
        const long long stride = (long long)(gridDim.x - ROWS) * 512;
        for (long long i = (long long)(blockIdx.x - ROWS) * 512 + threadIdx.x;
             i < nz4; i += stride)
            mz[i] = z4;
    }
}

// Fallback-path helper: re-zero the mask tail that temporarily held affinity.
__global__ void tailzero_kernel(float* __restrict__ out)
{
    const long long n4 = (long long)(AFF_ELEMS >> 2); // 65536 float4s
    float4* mz = (float4*)(out + MASK_OFF + MASK_ELEMS - AFF_ELEMS);
    const long long i = (long long)blockIdx.x * blockDim.x + threadIdx.x;
    if (i < n4) mz[i] = make_float4(0.f, 0.f, 0.f, 0.f);
}

// Scatter the one-hot ones (after all zeroing is globally done).
__global__ void scatter_kernel(float* __restrict__ out)
{
    const int p = blockIdx.x * blockDim.x + threadIdx.x;
    if (p < (int)IDX_ELEMS) {
        const int idx = (int)out[p];
        out[MASK_OFF + (size_t)p * SEQ + idx] = 1.0f;
    }
}

extern "C" void kernel_launch(void* const* d_in, const int* in_sizes, int n_in,
                              void* d_out, int out_size, void* d_ws, size_t ws_size,
                              hipStream_t stream)
{
    const float* hidden = (const float*)d_in[0];
    const float* weight = (const float*)d_in[1];
    float* out = (float*)d_out;

    // Affinity scratch [b][e][s] fp32 = 1 MB. Prefer d_ws; else borrow the
    // mask tail (excluded from the fused zero, re-zeroed after the sort).
    const bool use_ws = (ws_size >= AFF_ELEMS * sizeof(float));
    float* aff = use_ws ? (float*)d_ws
                        : (out + MASK_OFF + MASK_ELEMS - AFF_ELEMS);

    gating_kernel<<<2048, 128, 0, stream>>>(hidden, weight, aff);

    const long long zero_elems = use_ws ? (long long)MASK_ELEMS
                                        : (long long)(MASK_ELEMS - AFF_ELEMS);
    topk_zero_kernel<<<ROWS + 2048, 512, 0, stream>>>(aff, out, zero_elems);

    if (!use_ws)
        tailzero_kernel<<<256, 256, 0, stream>>>(out);

    scatter_kernel<<<(int)((IDX_ELEMS + 255) / 256), 256, 0, stream>>>(out);
}

// Round 8
// 648.139 us; speedup vs baseline: 1.0094x; 1.0094x over previous
//
#include <hip/hip_runtime.h>

constexpr int BSZ = 8, SEQ = 4096, HID = 1024, NE = 8, CAP = 512;
constexpr int ROWS = BSZ * NE;                          // 64
constexpr size_t IDX_ELEMS = (size_t)ROWS * CAP;        // 32768
constexpr size_t SCR_OFF = IDX_ELEMS;                   // 32768
constexpr size_t MASK_OFF = IDX_ELEMS * 2;              // 65536
constexpr size_t MASK_ELEMS = (size_t)ROWS * CAP * SEQ; // 134217728
constexpr size_t AFF_ELEMS = (size_t)ROWS * SEQ;        // 262144 floats (1 MB)

// ---------------------------------------------------------------------------
// Gating — BYTE-IDENTICAL to the R6 kernel that passed absmax=0.
// np.einsum fp32 SOP: 4-lane accumulator (lane j = d mod 4), blocks of 16,
// x4-unrolled reversed chained mul+add (no FMA), SSE3 double-hadd hsum
// (v0+v1)+(v2+v3). Softmax: max, fsub, CR fp32 exp, pairwise-8 tree, fp32 div.
// ---------------------------------------------------------------------------
__global__ __launch_bounds__(128) void gating_kernel(const float* __restrict__ hidden,
                                                     const float* __restrict__ weight,
                                                     float* __restrict__ aff)
{
    __shared__ float hls[16][68]; // 16 tokens x 64-d chunk (pad to 68)
    __shared__ float wls[8][68];  // transposed weight chunk: [e][dd]
    __shared__ float lls[16][8];  // logits exchange

    const int tid = threadIdx.x;
    const int T0 = blockIdx.x * 16;
    const int t = tid >> 3;       // token within block
    const int e = tid & 7;        // expert

    float v0 = 0.f, v1 = 0.f, v2 = 0.f, v3 = 0.f; // SSE lanes j=0..3
    for (int c = 0; c < 16; ++c) {
        __syncthreads(); // protect previous chunk's reads
        // stage hidden chunk: 256 float4s, coalesced
#pragma unroll
        for (int k = 0; k < 2; ++k) {
            const int j = tid + k * 128;      // 0..255
            const int tt = j >> 4, q = j & 15;
            const float4 v = *(const float4*)(hidden + (size_t)(T0 + tt) * HID + c * 64 + 4 * q);
            *(float4*)&hls[tt][4 * q] = v;
        }
        // stage weight chunk transposed: 512 scalars, coalesced global reads
#pragma unroll
        for (int k = 0; k < 4; ++k) {
            const int j = tid + k * 128;      // 0..511 == dd*8+ee
            const int dd = j >> 3, ee = j & 7;
            wls[ee][dd] = weight[(size_t)(c * 64 + dd) * NE + ee];
        }
        __syncthreads();
        // four 16-float blocks per chunk, numpy SOP order
#pragma unroll
        for (int k = 0; k < 4; ++k) {
            const int base = 16 * k;
            const float4 hA = *(const float4*)&hls[t][base + 0];
            const float4 hB = *(const float4*)&hls[t][base + 4];
            const float4 hC = *(const float4*)&hls[t][base + 8];
            const float4 hD = *(const float4*)&hls[t][base + 12];
            const float4 wA = *(const float4*)&wls[e][base + 0];
            const float4 wB = *(const float4*)&wls[e][base + 4];
            const float4 wC = *(const float4*)&wls[e][base + 8];
            const float4 wD = *(const float4*)&wls[e][base + 12];
            // v = a0*b0 + (a1*b1 + (a2*b2 + (a3*b3 + v))), per lane, no FMA
            v0 = __fadd_rn(__fmul_rn(hA.x, wA.x),
                 __fadd_rn(__fmul_rn(hB.x, wB.x),
                 __fadd_rn(__fmul_rn(hC.x, wC.x),
                 __fadd_rn(__fmul_rn(hD.x, wD.x), v0))));
            v1 = __fadd_rn(__fmul_rn(hA.y, wA.y),
                 __fadd_rn(__fmul_rn(hB.y, wB.y),
                 __fadd_rn(__fmul_rn(hC.y, wC.y),
                 __fadd_rn(__fmul_rn(hD.y, wD.y), v1))));
            v2 = __fadd_rn(__fmul_rn(hA.z, wA.z),
                 __fadd_rn(__fmul_rn(hB.z, wB.z),
                 __fadd_rn(__fmul_rn(hC.z, wC.z),
                 __fadd_rn(__fmul_rn(hD.z, wD.z), v2))));
            v3 = __fadd_rn(__fmul_rn(hA.w, wA.w),
                 __fadd_rn(__fmul_rn(hB.w, wB.w),
                 __fadd_rn(__fmul_rn(hC.w, wC.w),
                 __fadd_rn(__fmul_rn(hD.w, wD.w), v3))));
        }
    }
    // npyv_sum_f32 with SSE3 (manylinux baseline): double hadd = (v0+v1)+(v2+v3)
    const float logit = __fadd_rn(__fadd_rn(v0, v1), __fadd_rn(v2, v3));

    lls[t][e] = logit;
    __syncthreads();

    float l[8];
#pragma unroll
    for (int k = 0; k < 8; ++k) l[k] = lls[t][k];
    float m = l[0];
#pragma unroll
    for (int k = 1; k < 8; ++k) m = fmaxf(m, l[k]);
    float p[8];
#pragma unroll
    for (int k = 0; k < 8; ++k)
        p[k] = (float)exp((double)__fsub_rn(l[k], m)); // correctly-rounded fp32 exp
    const float s = __fadd_rn(__fadd_rn(__fadd_rn(p[0], p[1]), __fadd_rn(p[2], p[3])),
                              __fadd_rn(__fadd_rn(p[4], p[5]), __fadd_rn(p[6], p[7])));
    const float a = __fdiv_rn(p[e], s);

    const int token = T0 + t;
    const int b = token >> 12;
    const int sidx = token & (SEQ - 1);
    aff[((size_t)b * NE + e) * SEQ + sidx] = a;
}

// ---------------------------------------------------------------------------
// Fused top-k + zero-fill — R6 logic, ONLY change: 1024 threads per block
// (value-neutral: bitonic CE pairs within a pass are disjoint; zero writes
// zeros). Sort blocks do 2 CE iterations per pass instead of 4.
// ---------------------------------------------------------------------------
__global__ __launch_bounds__(1024) void topk_zero_kernel(const float* __restrict__ aff,
                                                         float* __restrict__ out,
                                                         long long zero_elems)
{
    __shared__ unsigned long long keys[SEQ]; // 32 KB
    if (blockIdx.x < (unsigned)ROWS) {
        const int row = blockIdx.x;
        const float* a = aff + (size_t)row * SEQ;
        for (int i = threadIdx.x; i < SEQ; i += 1024) {
            const unsigned int fb = __float_as_uint(a[i]);
            keys[i] = ((unsigned long long)fb << 32) | (unsigned int)(SEQ - 1 - i);
        }
        for (int len = 2; len <= SEQ; len <<= 1) {
            for (int stride = len >> 1; stride > 0; stride >>= 1) {
                __syncthreads();
                for (int t = threadIdx.x; t < SEQ / 2; t += 1024) {
                    const int i = (t << 1) - (t & (stride - 1));
                    const int j = i + stride;
                    const unsigned long long ki = keys[i], kj = keys[j];
                    const bool desc = ((i & len) == 0);
                    if (desc ? (ki < kj) : (ki > kj)) { keys[i] = kj; keys[j] = ki; }
                }
            }
        }
        __syncthreads();
        if (threadIdx.x < CAP) {
            const int t = threadIdx.x;
            const unsigned long long k = keys[t];
            const int idx = (SEQ - 1) - (int)(unsigned int)(k & 0xffffffffu);
            out[(size_t)row * CAP + t] = (float)idx;                         // indices
            out[SCR_OFF + (size_t)row * CAP + t] =
                __uint_as_float((unsigned int)(k >> 32));                    // scores
        }
    } else {
        const long long nz4 = zero_elems >> 2;
        float4* mz = (float4*)(out + MASK_OFF);
        const float4 z4 = make_float4(0.f, 0.f, 0.f, 0.f);
        const long long stride = (long long)(gridDim.x - ROWS) * 1024;
        for (long long i = (long long)(blockIdx.x - ROWS) * 1024 + threadIdx.x;
             i < nz4; i += stride)
            mz[i] = z4;
    }
}

// Fallback-path helper: re-zero the mask tail that temporarily held affinity.
__global__ void tailzero_kernel(float* __restrict__ out)
{
    const long long n4 = (long long)(AFF_ELEMS >> 2); // 65536 float4s
    float4* mz = (float4*)(out + MASK_OFF + MASK_ELEMS - AFF_ELEMS);
    const long long i = (long long)blockIdx.x * blockDim.x + threadIdx.x;
    if (i < n4) mz[i] = make_float4(0.f, 0.f, 0.f, 0.f);
}

// Scatter the one-hot ones (after all zeroing is globally done).
__global__ void scatter_kernel(float* __restrict__ out)
{
    const int p = blockIdx.x * blockDim.x + threadIdx.x;
    if (p < (int)IDX_ELEMS) {
        const int idx = (int)out[p];
        out[MASK_OFF + (size_t)p * SEQ + idx] = 1.0f;
    }
}

extern "C" void kernel_launch(void* const* d_in, const int* in_sizes, int n_in,
                              void* d_out, int out_size, void* d_ws, size_t ws_size,
                              hipStream_t stream)
{
    const float* hidden = (const float*)d_in[0];
    const float* weight = (const float*)d_in[1];
    float* out = (float*)d_out;

    // Affinity scratch [b][e][s] fp32 = 1 MB. Prefer d_ws; else borrow the
    // mask tail (excluded from the fused zero, re-zeroed after the sort).
    const bool use_ws = (ws_size >= AFF_ELEMS * sizeof(float));
    float* aff = use_ws ? (float*)d_ws
                        : (out + MASK_OFF + MASK_ELEMS - AFF_ELEMS);

    gating_kernel<<<2048, 128, 0, stream>>>(hidden, weight, aff);

    const long long zero_elems = use_ws ? (long long)MASK_ELEMS
                                        : (long long)(MASK_ELEMS - AFF_ELEMS);
    topk_zero_kernel<<<ROWS + 1984, 1024, 0, stream>>>(aff, out, zero_elems);

    if (!use_ws)
        tailzero_kernel<<<256, 256, 0, stream>>>(out);

    scatter_kernel<<<(int)((IDX_ELEMS + 255) / 256), 256, 0, stream>>>(out);
}